// Round 16
// baseline (123.829 us; speedup 1.0000x reference)
//
#include <hip/hip_runtime.h>

#define NTOK   131072
#define KCODES 1024
#define DIM    64
#define BM     128
#define BN     64
#define NCT    (KCODES / BN)         // 16 code tiles
#define SLOT_CAP 16384               // worklist capacity

#define LOSS_OFF (NTOK * DIM)        // 8388608
#define IDX_OFF  (LOSS_OFF + 1)      // 8388609

#define EPS_U 3e-5f                  // u-gap threshold; worst-case err ~4e-6

typedef __attribute__((ext_vector_type(8))) short bf16x8;
typedef __attribute__((ext_vector_type(4))) float f32x4;
typedef __attribute__((ext_vector_type(4))) unsigned short ush4;

#if defined(__has_builtin)
#if __has_builtin(__builtin_amdgcn_global_load_lds)
#define HAVE_GLD 1
#endif
#if __has_builtin(__builtin_amdgcn_fmed3f)
#define MED3(a,b,c) __builtin_amdgcn_fmed3f((a),(b),(c))
#endif
#endif
#ifndef MED3
#define MED3(a,b,c) fminf((a), fmaxf((b),(c)))
#endif

#ifdef HAVE_GLD
typedef const __attribute__((address_space(1))) unsigned int* gas_u32p;
typedef __attribute__((address_space(3))) unsigned int* las_u32p;
#define GLD16(ldst, gsrc) \
    __builtin_amdgcn_global_load_lds((gas_u32p)(gsrc), (las_u32p)(ldst), 16, 0, 0)
#endif

__device__ inline unsigned short bf16rtn(float x) {
    unsigned u = __float_as_uint(x);
    return (unsigned short)((u + 0x7fffu + ((u >> 16) & 1u)) >> 16);
}

// monotone float->u32 map; packed with idx so u64-min == lex (d, idx) min.
__device__ inline unsigned long long packdi(float d, int idx) {
    unsigned b = __float_as_uint(d);
    b ^= (b & 0x80000000u) ? 0xFFFFFFFFu : 0x80000000u;
    return ((unsigned long long)b << 32) | (unsigned)idx;
}

// ---- K0: split E -> bf16 hi|lo PRE-SWIZZLED per-code-row layout, esq, clear cnt
__global__ __launch_bounds__(256) void prep_kernel(const float* __restrict__ E,
                                                   unsigned short* __restrict__ Bswz,
                                                   float* __restrict__ esqh,
                                                   float* __restrict__ esq,
                                                   int* __restrict__ cnt) {
    const int t = threadIdx.x, b = blockIdx.x;
    if (b == 0 && t == 0) cnt[0] = 0;
    int id = b * 256 + t;                      // 65536 = 1024 x 64
    int c = id >> 6, k = id & 63;
    float x = E[id];
    unsigned short h = bf16rtn(x);
    float hf = __uint_as_float(((unsigned)h) << 16);
    unsigned short lo = bf16rtn(x - hf);
    int rx = (c & 7) << 4;
    int qh = (k >> 3) << 4;                    // 16B chunk byte offset
    int ob = (k & 7) << 1;                     // byte within chunk
    Bswz[(c * 256 + (qh ^ rx) + ob) >> 1]           = h;
    Bswz[(c * 256 + ((128 + qh) ^ rx) + ob) >> 1]   = lo;
    if (b < 4) {                               // esq: arithmetic verbatim (R1-R15)
        int cc = b * 256 + t;
        const float4* row = (const float4*)(E + cc * DIM);
        float s = 0.f;
        #pragma unroll
        for (int i = 0; i < DIM / 4; ++i) {
            float4 v = row[i];
            s += v.x * v.x + v.y * v.y + v.z * v.z + v.w * v.w;
        }
        esq[cc] = s;
        esqh[cc] = 0.5f * s;                   // exact
    }
}

// ------------------------------------------------- K1: MFMA distances + argmin
// R15 structure VERBATIM except __launch_bounds__(512,8): R15 measured 56 VGPR
// (<= the 64 cap of 8 waves/EU) and 53248B LDS (3 blocks/CU fit) — single-
// variable occupancy test: 16 -> 24 waves/CU to hide barrier convoys.
__global__ __launch_bounds__(512, 8) void mfma_argmin_kernel(
    const float* __restrict__ z, const float* __restrict__ E,
    const unsigned short* __restrict__ Bswz, const float* __restrict__ esqh_g,
    float* __restrict__ idx_out, float* __restrict__ out0,
    float* __restrict__ partials, int* __restrict__ cnt, int* __restrict__ wl,
    unsigned long long* __restrict__ bitmap) {
    __shared__ __align__(16) char lds[49152];  // 3 x 16KB Bs; A staged here pre-loop
    __shared__ __align__(16) char aux[4096];
    float* esqh_s  = (float*)aux;              // dead after main loop
    float* cb_best = (float*)aux;              // [2][128]
    float* cb_sec  = (float*)(aux + 1024);
    int*   cb_idx  = (int*)(aux + 2048);
    int*   fbi     = (int*)(aux + 3072);       // [128] packed idx|flag
    float* wred    = (float*)(aux + 3584);     // [8]

    const int t = threadIdx.x;
    const int l = t & 63;
    const int w = t >> 6;            // wave 0..7
    const int rg = w >> 1;           // row group (32 tokens)
    const int cg = w & 1;            // col group (32 codes)
    const int lan15 = l & 15;
    const int kp16 = (l >> 4) * 16;
    const int xr = (lan15 & 7) << 4;
    const int row0 = blockIdx.x * BM;
    const char* gb = (const char*)Bswz;

    esqh_s[t]       = esqh_g[t];
    esqh_s[512 + t] = esqh_g[512 + t];

    // z load + hi/lo split -> A-hi [0,16K), A-lo [16K,32K)
    {
        const float4* zg = (const float4*)(z + (size_t)row0 * DIM);
        float4 av[4];
        #pragma unroll
        for (int p = 0; p < 4; ++p) av[p] = zg[p * 512 + t];
        #pragma unroll
        for (int p = 0; p < 4; ++p) {
            int li = p * 512 + t;
            int r = li >> 4, q = li & 15;
            float xs[4] = {av[p].x, av[p].y, av[p].z, av[p].w};
            ush4 hv, lv;
            #pragma unroll
            for (int j = 0; j < 4; ++j) {
                unsigned short h = bf16rtn(xs[j]);
                float hf = __uint_as_float(((unsigned)h) << 16);
                hv[j] = h;
                lv[j] = bf16rtn(xs[j] - hf);
            }
            int rxw = (r & 7) << 4;
            int o = ((q * 8) ^ rxw);
            *(ush4*)(lds + r * 128 + o)         = hv;
            *(ush4*)(lds + 16384 + r * 128 + o) = lv;
        }
    }
    __syncthreads();

    const int ko0 = kp16 ^ xr;
    const int ko1 = (64 + kp16) ^ xr;
    const int arow = (rg * 32 + lan15) * 128;

    // all 8 A fragments -> registers (ct-invariant)
    bf16x8 ah00 = *(const bf16x8*)(lds + arow + ko0);
    bf16x8 ah01 = *(const bf16x8*)(lds + arow + ko1);
    bf16x8 ah10 = *(const bf16x8*)(lds + arow + 2048 + ko0);
    bf16x8 ah11 = *(const bf16x8*)(lds + arow + 2048 + ko1);
    bf16x8 al00 = *(const bf16x8*)(lds + 16384 + arow + ko0);
    bf16x8 al01 = *(const bf16x8*)(lds + 16384 + arow + ko1);
    bf16x8 al10 = *(const bf16x8*)(lds + 16384 + arow + 2048 + ko0);
    bf16x8 al11 = *(const bf16x8*)(lds + 16384 + arow + 2048 + ko1);
    __syncthreads();                 // all A reads retired; region -> Bs bufs

    // prefetch tiles 0 (->Bs0) and 1 (->Bs1)
#ifdef HAVE_GLD
    GLD16(lds + t * 16,         gb + t * 16);
    GLD16(lds + 8192 + t * 16,  gb + 8192 + t * 16);
    GLD16(lds + 16384 + t * 16, gb + 16384 + t * 16);
    GLD16(lds + 24576 + t * 16, gb + 24576 + t * 16);
    asm volatile("s_waitcnt vmcnt(2)" ::: "memory");   // tile0 landed
    __builtin_amdgcn_sched_barrier(0);
    __builtin_amdgcn_s_barrier();
    __builtin_amdgcn_sched_barrier(0);
#else
    #pragma unroll
    for (int p = 0; p < 4; ++p)
        *(uint4*)(lds + p * 8192 + t * 16) = *(const uint4*)(gb + p * 8192 + t * 16);
    __syncthreads();
#endif

    float best[8], second[8];
    int   bidx[8];
    #pragma unroll
    for (int s = 0; s < 8; ++s) { best[s] = 3.4e38f; second[s] = 3.4e38f; bidx[s] = 0; }

    const int brow = (cg * 32 + lan15) * 256;  // + fc*4096 (imm)

    for (int ct = 0; ct < NCT; ++ct) {         // ROLLED (R14 lesson)
        const char* cur = lds + (ct % 3) * 16384;
#ifdef HAVE_GLD
        if (ct < NCT - 2) {                    // issue tile ct+2 -> (ct+2)%3
            char* nbuf = lds + ((ct + 2) % 3) * 16384;
            const char* g = gb + (size_t)(ct + 2) * 16384;
            GLD16(nbuf + t * 16,        g + t * 16);
            GLD16(nbuf + 8192 + t * 16, g + 8192 + t * 16);
        }
#else
        uint4 pva, pvb;
        if (ct < NCT - 2) {
            const char* g = gb + (size_t)(ct + 2) * 16384;
            pva = *(const uint4*)(g + t * 16);
            pvb = *(const uint4*)(g + 8192 + t * 16);
        }
#endif

        f32x4 acc[2][2];
        #pragma unroll
        for (int fr = 0; fr < 2; ++fr)
            #pragma unroll
            for (int fc = 0; fc < 2; ++fc)
                acc[fr][fc] = (f32x4){0.f, 0.f, 0.f, 0.f};

        // per-acc term order FP-identical to R6-R15: hh,hh,lh,lh,hl,hl
        #pragma unroll
        for (int fc = 0; fc < 2; ++fc) {
            const char* bp = cur + brow + fc * 4096;
            bf16x8 b0 = *(const bf16x8*)(bp + ko0);
            bf16x8 b1 = *(const bf16x8*)(bp + ko1);
            acc[0][fc] = __builtin_amdgcn_mfma_f32_16x16x32_bf16(ah00, b0, acc[0][fc], 0, 0, 0);
            acc[1][fc] = __builtin_amdgcn_mfma_f32_16x16x32_bf16(ah10, b0, acc[1][fc], 0, 0, 0);
            acc[0][fc] = __builtin_amdgcn_mfma_f32_16x16x32_bf16(ah01, b1, acc[0][fc], 0, 0, 0);
            acc[1][fc] = __builtin_amdgcn_mfma_f32_16x16x32_bf16(ah11, b1, acc[1][fc], 0, 0, 0);
            acc[0][fc] = __builtin_amdgcn_mfma_f32_16x16x32_bf16(al00, b0, acc[0][fc], 0, 0, 0);
            acc[1][fc] = __builtin_amdgcn_mfma_f32_16x16x32_bf16(al10, b0, acc[1][fc], 0, 0, 0);
            acc[0][fc] = __builtin_amdgcn_mfma_f32_16x16x32_bf16(al01, b1, acc[0][fc], 0, 0, 0);
            acc[1][fc] = __builtin_amdgcn_mfma_f32_16x16x32_bf16(al11, b1, acc[1][fc], 0, 0, 0);
            {
                bf16x8 b2 = *(const bf16x8*)(bp + 128 + ko0);
                acc[0][fc] = __builtin_amdgcn_mfma_f32_16x16x32_bf16(ah00, b2, acc[0][fc], 0, 0, 0);
                acc[1][fc] = __builtin_amdgcn_mfma_f32_16x16x32_bf16(ah10, b2, acc[1][fc], 0, 0, 0);
            }
            {
                bf16x8 b3 = *(const bf16x8*)(bp + 128 + ko1);
                acc[0][fc] = __builtin_amdgcn_mfma_f32_16x16x32_bf16(ah01, b3, acc[0][fc], 0, 0, 0);
                acc[1][fc] = __builtin_amdgcn_mfma_f32_16x16x32_bf16(ah11, b3, acc[1][fc], 0, 0, 0);
            }
        }

        // epilogue: u = esq/2 - dot; (best, second=med3, idx)
        #pragma unroll
        for (int fc = 0; fc < 2; ++fc) {
            int col = ct * BN + cg * 32 + fc * 16 + lan15;
            float eh = esqh_s[col];
            #pragma unroll
            for (int fr = 0; fr < 2; ++fr) {
                #pragma unroll
                for (int r = 0; r < 4; ++r) {
                    float u = eh - acc[fr][fc][r];
                    int s = fr * 4 + r;
                    second[s] = MED3(second[s], u, best[s]);
                    bidx[s] = (u < best[s]) ? col : bidx[s];
                    best[s] = fminf(u, best[s]);
                }
            }
        }

        // ct-end sync: counted vmcnt keeps tile ct+2 in flight across barrier
#ifdef HAVE_GLD
        if (ct < NCT - 2) {
            asm volatile("s_waitcnt vmcnt(2) lgkmcnt(0)" ::: "memory");
        } else if (ct == NCT - 2) {
            asm volatile("s_waitcnt vmcnt(0) lgkmcnt(0)" ::: "memory");
        } else {
            asm volatile("s_waitcnt lgkmcnt(0)" ::: "memory");
        }
        __builtin_amdgcn_sched_barrier(0);
        __builtin_amdgcn_s_barrier();
        __builtin_amdgcn_sched_barrier(0);
#else
        __syncthreads();
        if (ct < NCT - 2) {
            char* nbuf = lds + ((ct + 2) % 3) * 16384;
            *(uint4*)(nbuf + t * 16)        = pva;
            *(uint4*)(nbuf + 8192 + t * 16) = pvb;
        }
        __syncthreads();
#endif
    }

    // intra-wave reduce over 16-lane groups (lex: ties -> smaller col)
    #pragma unroll
    for (int s = 0; s < 8; ++s) {
        float b = best[s], sc = second[s];
        int bi = bidx[s];
        #pragma unroll
        for (int off = 1; off <= 8; off <<= 1) {
            float ob = __shfl_xor(b, off);
            float os = __shfl_xor(sc, off);
            int   oi = __shfl_xor(bi, off);
            float mx = fmaxf(b, ob);
            sc = fminf(fminf(sc, os), mx);
            if (ob < b) { b = ob; bi = oi; }
            else if (ob == b) bi = min(bi, oi);
        }
        best[s] = b; second[s] = sc; bidx[s] = bi;
    }
    if (lan15 == 0) {
        #pragma unroll
        for (int s = 0; s < 8; ++s) {
            int row = rg * 32 + (s >> 2) * 16 + (l >> 4) * 4 + (s & 3);
            cb_best[cg * BM + row] = best[s];
            cb_sec [cg * BM + row] = second[s];
            cb_idx [cg * BM + row] = bidx[s];
        }
    }
    __syncthreads();
    // cross-wave combine + flag emit
    if (t < BM) {
        float b0 = cb_best[t], b1 = cb_best[BM + t];
        float s0 = cb_sec[t],  s1 = cb_sec[BM + t];
        int   i0 = cb_idx[t],  i1 = cb_idx[BM + t];
        float b; int bi;
        if (b1 < b0 || (b1 == b0 && i1 < i0)) { b = b1; bi = i1; }
        else                                  { b = b0; bi = i0; }
        float sec = fminf(fminf(s0, s1), fmaxf(b0, b1));
        int gid = row0 + t;
        idx_out[gid] = (float)bi;
        bool flg = (sec - b <= EPS_U);
        fbi[t] = bi | (flg ? 0x80000000 : 0);
        unsigned long long mask = __ballot(flg);
        if (l == 0) bitmap[blockIdx.x * 2 + w] = mask;   // full-word, no init
        int nf = __popcll(mask);
        int base = 0;
        if (l == 0 && nf) base = atomicAdd(cnt, nf);
        base = __shfl(base, 0);
        if (flg) {
            int pos = __popcll(mask & ((1ull << l) - 1ull));
            int slot = base + pos;
            if (slot < SLOT_CAP) wl[slot] = gid;
        }
    }
    __syncthreads();                 // fbi visible to all waves

    // ---- fused gather tail: z_q_st rows + per-block loss partial ----
    {
        const int tk = t >> 2, qd = t & 3;
        int pk = fbi[tk];
        int bi = pk & 0x3FF;
        bool fl = pk < 0;
        const float4* zr = (const float4*)z + (size_t)(row0 + tk) * 16 + qd * 4;
        const float4* er = (const float4*)E + (size_t)bi * 16 + qd * 4;
        float4* orow = (float4*)out0 + (size_t)(row0 + tk) * 16 + qd * 4;
        float ls = 0.f;
        #pragma unroll
        for (int j = 0; j < 4; ++j) {
            float4 zv = zr[j], ev = er[j];
            float dx = ev.x - zv.x, dy = ev.y - zv.y;
            float dz = ev.z - zv.z, dw = ev.w - zv.w;
            float4 o = {zv.x + dx, zv.y + dy, zv.z + dz, zv.w + dw};
            orow[j] = o;
            ls += dx * dx + dy * dy + dz * dz + dw * dw;
        }
        if (fl) ls = 0.f;            // flagged: exact contrib comes from repair
        #pragma unroll
        for (int off = 1; off <= 32; off <<= 1) ls += __shfl_xor(ls, off);
        if (l == 0) wred[w] = ls;
    }
    __syncthreads();
    if (t == 0) {
        float s = 0.f;
        #pragma unroll
        for (int i = 0; i < 8; ++i) s += wred[i];
        partials[blockIdx.x] = s;
    }
}

// ---- K2: exact recompute, QUARTER-SPLIT (R2-pedigree staging + FMA chain)
__global__ __launch_bounds__(256) void fallback_kernel(
    const float* __restrict__ z, const float* __restrict__ E,
    const float* __restrict__ esq_g, unsigned long long* __restrict__ cand,
    const int* __restrict__ wl, const int* __restrict__ cnt_p) {
    __shared__ __align__(16) float es[DIM][128];   // 32KB [k][code]
    __shared__ __align__(16) float zl[16][72];     // padded
    __shared__ float zqs[16];

    const int t = threadIdx.x;
    const int tg = t >> 4;           // token slot 0..15
    const int cs = t & 15;           // code slice (8 codes per tile)
    const int cnt = min(*cnt_p, SLOT_CAP);
    const int nwork = ((cnt + 15) >> 4) << 2;      // chunks * 4 quarters

    for (int cb = blockIdx.x; cb < nwork; cb += 2048) {
        const int chunk = cb >> 2, qtr = cb & 3;
        const int base = chunk * 16;
        const int nval = min(16, cnt - base);
        const int tok = wl[base + (tg < nval ? tg : 0)];
        {
            float4 v = ((const float4*)z)[(size_t)tok * 16 + cs];
            *(float4*)&zl[tg][cs * 4] = v;
        }
        __syncthreads();
        if (t < 16) {                // zq per slot, sequential k (as R1)
            float s = 0.f;
            for (int k = 0; k < DIM; ++k) { float v = zl[t][k]; s += v * v; }
            zqs[t] = s;
        }
        __syncthreads();
        const float zq = zqs[tg];

        float best = 3.4e38f;
        int bi = 0;
        for (int ti = 0; ti < 2; ++ti) {         // 2 tiles of this quarter
            const int tile = qtr * 2 + ti;
            const float4* eg = (const float4*)(E + (size_t)tile * 128 * DIM);
            #pragma unroll
            for (int p = 0; p < 8; ++p) {        // R2 staging pattern verbatim
                int li = p * 256 + t;
                int c = li & 127, k4 = li >> 7;
                float4 v = eg[c * 16 + k4];
                es[k4 * 4 + 0][c] = v.x;
                es[k4 * 4 + 1][c] = v.y;
                es[k4 * 4 + 2][c] = v.z;
                es[k4 * 4 + 3][c] = v.w;
            }
            __syncthreads();

            float acc[8];
            #pragma unroll
            for (int n = 0; n < 8; ++n) acc[n] = 0.f;
            #pragma unroll 8
            for (int k = 0; k < DIM; ++k) {      // sequential fp32 FMA over K
                float a = zl[tg][k];
                float4 b0 = *(const float4*)&es[k][cs * 8 + 0];
                float4 b1 = *(const float4*)&es[k][cs * 8 + 4];
                float b[8] = {b0.x, b0.y, b0.z, b0.w, b1.x, b1.y, b1.z, b1.w};
                #pragma unroll
                for (int n = 0; n < 8; ++n) acc[n] += a * b[n];
            }
            #pragma unroll
            for (int n = 0; n < 8; ++n) {        // ascending code index, strict <
                int c = tile * 128 + cs * 8 + n;
                float d = (zq - 2.0f * acc[n]) + esq_g[c];
                if (d < best) { best = d; bi = c; }
            }
            __syncthreads();
        }
        #pragma unroll
        for (int off = 1; off <= 8; off <<= 1) {
            float ob = __shfl_xor(best, off);
            int   oi = __shfl_xor(bi, off);
            if (ob < best || (ob == best && oi < bi)) { best = ob; bi = oi; }
        }
        if (cs == 0 && tg < nval)
            cand[(size_t)(base + tg) * 4 + qtr] = packdi(best, bi);
        __syncthreads();
    }
}

// ---- K3: repair flagged tokens (u64-min of 4 quarter candidates)
__global__ __launch_bounds__(256) void repair_kernel(
    const float* __restrict__ z, const float* __restrict__ E,
    float* __restrict__ idx_out, float* __restrict__ out0,
    float* __restrict__ contrib, const unsigned long long* __restrict__ cand,
    const int* __restrict__ wl, const int* __restrict__ cnt_p) {
    const int t = threadIdx.x;
    const int tg = t >> 4;           // token slot 0..15
    const int cs = t & 15;           // float4 chunk of dim
    const int cnt = min(*cnt_p, SLOT_CAP);

    for (int s0 = blockIdx.x * 16; s0 < cnt; s0 += 512 * 16) {
        int s = s0 + tg;
        if (s < cnt) {
            int tok = wl[s];
            unsigned long long m = cand[(size_t)s * 4 + 0];
            m = min(m, cand[(size_t)s * 4 + 1]);
            m = min(m, cand[(size_t)s * 4 + 2]);
            m = min(m, cand[(size_t)s * 4 + 3]);
            int bi = (int)(unsigned)(m & 0xFFFFFFFFull);
            float4 zv = ((const float4*)z)[(size_t)tok * 16 + cs];
            float4 ev = ((const float4*)E)[(size_t)bi * 16 + cs];
            float dx = ev.x - zv.x, dy = ev.y - zv.y;
            float dz = ev.z - zv.z, dw = ev.w - zv.w;
            float4 o = {zv.x + dx, zv.y + dy, zv.z + dz, zv.w + dw};
            ((float4*)out0)[(size_t)tok * 16 + cs] = o;
            float c4 = dx * dx + dy * dy + dz * dz + dw * dw;
            #pragma unroll
            for (int off = 1; off <= 8; off <<= 1) c4 += __shfl_xor(c4, off);
            if (cs == 0) {
                idx_out[tok] = (float)bi;
                contrib[tok] = c4;
            }
        }
    }
}

// -------- K4: final loss = (sum partials + sum flagged contribs) scaled
__global__ __launch_bounds__(256) void loss_kernel(
    const float* __restrict__ partials, const unsigned long long* __restrict__ bitmap,
    const float* __restrict__ contrib, float* __restrict__ loss_out) {
    __shared__ float red[256];
    const int t = threadIdx.x;
    float p = 0.f;
    #pragma unroll
    for (int i = 0; i < 4; ++i) p += partials[t * 4 + i];
    for (int wi = t * 8; wi < t * 8 + 8; ++wi) {   // fixed token order per thread
        unsigned long long m = bitmap[wi];
        while (m) {
            int b = __builtin_ctzll(m);
            p += contrib[wi * 64 + b];
            m &= m - 1;
        }
    }
    red[t] = p;
    __syncthreads();
    for (int s = 128; s >= 1; s >>= 1) {
        if (t < s) red[t] += red[t + s];
        __syncthreads();
    }
    if (t == 0) {
        float m = red[0] / (float)(NTOK * DIM);
        loss_out[0] = m + 0.25f * m;
    }
}

extern "C" void kernel_launch(void* const* d_in, const int* in_sizes, int n_in,
                              void* d_out, int out_size, void* d_ws, size_t ws_size,
                              hipStream_t stream) {
    const float* z = (const float*)d_in[0];       // [131072, 64] f32
    const float* E = (const float*)d_in[1];       // [1024, 64] f32
    float* out = (float*)d_out;

    char* wsb = (char*)d_ws;
    float*              esq      = (float*)(wsb);               // 4 KB
    float*              esqh     = (float*)(wsb + 4096);        // 4 KB
    float*              partials = (float*)(wsb + 8192);        // 8 KB (1024 used)
    int*                cnt      = (int*)(wsb + 16384);         // 4 KB region
    int*                wl       = (int*)(wsb + 20480);         // 64 KB
    unsigned long long* bitmap   = (unsigned long long*)(wsb + 86016);  // 16 KB
    unsigned short*     Bswz     = (unsigned short*)(wsb + 102400);     // 256 KB
    float*              contrib  = (float*)(wsb + 364544);      // 512 KB
    unsigned long long* cand     = (unsigned long long*)(wsb + 888832); // 512 KB

    prep_kernel<<<256, 256, 0, stream>>>(E, Bswz, esqh, esq, cnt);
    mfma_argmin_kernel<<<NTOK / BM, 512, 0, stream>>>(z, E, Bswz, esqh,
                                                      out + IDX_OFF, out,
                                                      partials, cnt, wl, bitmap);
    fallback_kernel<<<2048, 256, 0, stream>>>(z, E, esq, cand, wl, cnt);
    repair_kernel<<<512, 256, 0, stream>>>(z, E, out + IDX_OFF, out, contrib,
                                           cand, wl, cnt);
    loss_kernel<<<1, 256, 0, stream>>>(partials, bitmap, contrib, out + LOSS_OFF);
}

// Round 17
// 119.918 us; speedup vs baseline: 1.0326x; 1.0326x over previous
//
#include <hip/hip_runtime.h>

#define NTOK   131072
#define KCODES 1024
#define DIM    64
#define BM     128
#define BN     128
#define NCT    (KCODES / BN)         // 8 code tiles
#define SLOT_CAP 16384               // worklist capacity

#define LOSS_OFF (NTOK * DIM)        // 8388608
#define IDX_OFF  (LOSS_OFF + 1)      // 8388609

#define EPS_U 3e-5f                  // u-gap threshold; worst-case err ~4e-6 -> 7.5x margin

typedef __attribute__((ext_vector_type(8))) short bf16x8;
typedef __attribute__((ext_vector_type(4))) float f32x4;
typedef __attribute__((ext_vector_type(4))) unsigned short ush4;

#if defined(__has_builtin)
#if __has_builtin(__builtin_amdgcn_global_load_lds)
#define HAVE_GLD 1
#endif
#endif

#ifdef HAVE_GLD
typedef const __attribute__((address_space(1))) unsigned int* gas_u32p;
typedef __attribute__((address_space(3))) unsigned int* las_u32p;
#define GLD16(ldst, gsrc) \
    __builtin_amdgcn_global_load_lds((gas_u32p)(gsrc), (las_u32p)(ldst), 16, 0, 0)
#endif

__device__ inline unsigned short bf16rtn(float x) {
    unsigned u = __float_as_uint(x);
    return (unsigned short)((u + 0x7fffu + ((u >> 16) & 1u)) >> 16);
}

// monotone float->u32 map; packed with idx so u64-min == lex (d, idx) min.
__device__ inline unsigned long long packdi(float d, int idx) {
    unsigned b = __float_as_uint(d);
    b ^= (b & 0x80000000u) ? 0xFFFFFFFFu : 0x80000000u;
    return ((unsigned long long)b << 32) | (unsigned)idx;
}

// ---- K0: split E -> bf16 hi|lo PRE-SWIZZLED per-code-row layout, esq, clear cnt
__global__ __launch_bounds__(256) void prep_kernel(const float* __restrict__ E,
                                                   unsigned short* __restrict__ Bswz,
                                                   float* __restrict__ esqh,
                                                   float* __restrict__ esq,
                                                   int* __restrict__ cnt) {
    const int t = threadIdx.x, b = blockIdx.x;
    if (b == 0 && t == 0) cnt[0] = 0;
    int id = b * 256 + t;                      // 65536 = 1024 x 64
    int c = id >> 6, k = id & 63;
    float x = E[id];
    unsigned short h = bf16rtn(x);
    float hf = __uint_as_float(((unsigned)h) << 16);
    unsigned short lo = bf16rtn(x - hf);
    int rx = (c & 7) << 4;
    int qh = (k >> 3) << 4;                    // 16B chunk byte offset
    int ob = (k & 7) << 1;                     // byte within chunk
    Bswz[(c * 256 + (qh ^ rx) + ob) >> 1]           = h;
    Bswz[(c * 256 + ((128 + qh) ^ rx) + ob) >> 1]   = lo;
    if (b < 4) {                               // esq: arithmetic verbatim (R1-R16)
        int cc = b * 256 + t;
        const float4* row = (const float4*)(E + cc * DIM);
        float s = 0.f;
        #pragma unroll
        for (int i = 0; i < DIM / 4; ++i) {
            float4 v = row[i];
            s += v.x * v.x + v.y * v.y + v.z * v.z + v.w * v.w;
        }
        esq[cc] = s;
        esqh[cc] = 0.5f * s;                   // exact
    }
}

// ------------------------------------------------- K1: MFMA distances + argmin
// 512 thr = 8 waves (4 rg x 2 cg); wave tile 32 tok x 64 codes (fr=2 x fc=4);
// BN=128 -> 8 code tiles, ONE barrier each. All 8 A-frags (hi+lo) ct-invariant
// in regs. B staged by global_load_lds from pre-swizzled global into 2x32KB
// dbuf (Bs0 overlays dead A-staging). Fused gather tail + loss partial + flags.
__global__ __launch_bounds__(512, 4) void mfma_argmin_kernel(
    const float* __restrict__ z, const float* __restrict__ E,
    const unsigned short* __restrict__ Bswz, const float* __restrict__ esqh_g,
    float* __restrict__ idx_out, float* __restrict__ out0,
    float* __restrict__ partials, int* __restrict__ cnt, int* __restrict__ wl,
    unsigned long long* __restrict__ bitmap) {
    // [0,32K): A-hi/A-lo staging, then Bs0 | [32K,64K): Bs1
    __shared__ __align__(16) char lds[65536];
    __shared__ __align__(16) char aux[4096];
    float* esqh_s  = (float*)aux;              // dead after main loop
    float* cb_best = (float*)aux;              // [2][128]
    float* cb_sec  = (float*)(aux + 1024);
    int*   cb_idx  = (int*)(aux + 2048);
    int*   fbi     = (int*)(aux + 3072);       // [128] packed idx|flag
    float* wred    = (float*)(aux + 3584);     // [8]

    const int t = threadIdx.x;
    const int l = t & 63;
    const int w = t >> 6;            // wave 0..7
    const int rg = w >> 1;           // row group (32 tokens)
    const int cg = w & 1;            // col group (64 codes)
    const int lan15 = l & 15;
    const int kp16 = (l >> 4) * 16;
    const int xr = (lan15 & 7) << 4;
    const int row0 = blockIdx.x * BM;
    const char* gb = (const char*)Bswz;

    // issue tile0 -> Bs1 [32K,64K) immediately (hides under prologue)
#ifdef HAVE_GLD
    #pragma unroll
    for (int p = 0; p < 4; ++p)
        GLD16(lds + 32768 + p * 8192 + t * 16, gb + p * 8192 + t * 16);
#else
    uint4 pv0[4];
    #pragma unroll
    for (int p = 0; p < 4; ++p)
        pv0[p] = *(const uint4*)(gb + p * 8192 + t * 16);
#endif

    esqh_s[t]       = esqh_g[t];
    esqh_s[512 + t] = esqh_g[512 + t];

    // z load + hi/lo split -> A-hi [0,16K), A-lo [16K,32K)
    {
        const float4* zg = (const float4*)(z + (size_t)row0 * DIM);
        float4 av[4];
        #pragma unroll
        for (int p = 0; p < 4; ++p) av[p] = zg[p * 512 + t];
        #pragma unroll
        for (int p = 0; p < 4; ++p) {
            int li = p * 512 + t;
            int r = li >> 4, q = li & 15;
            float xs[4] = {av[p].x, av[p].y, av[p].z, av[p].w};
            ush4 hv, lv;
            #pragma unroll
            for (int j = 0; j < 4; ++j) {
                unsigned short h = bf16rtn(xs[j]);
                float hf = __uint_as_float(((unsigned)h) << 16);
                hv[j] = h;
                lv[j] = bf16rtn(xs[j] - hf);
            }
            int rxw = (r & 7) << 4;
            int o = ((q * 8) ^ rxw);
            *(ush4*)(lds + r * 128 + o)         = hv;
            *(ush4*)(lds + 16384 + r * 128 + o) = lv;
        }
    }
#ifndef HAVE_GLD
    #pragma unroll
    for (int p = 0; p < 4; ++p)
        *(uint4*)(lds + 32768 + p * 8192 + t * 16) = pv0[p];
#endif
    __syncthreads();

    const int ko0 = kp16 ^ xr;
    const int ko1 = (64 + kp16) ^ xr;
    const int arow = (rg * 32 + lan15) * 128;

    // all 8 A fragments ct-invariant -> registers (32 VGPR)
    bf16x8 ah00 = *(const bf16x8*)(lds + arow + ko0);
    bf16x8 ah01 = *(const bf16x8*)(lds + arow + ko1);
    bf16x8 ah10 = *(const bf16x8*)(lds + arow + 2048 + ko0);
    bf16x8 ah11 = *(const bf16x8*)(lds + arow + 2048 + ko1);
    bf16x8 al00 = *(const bf16x8*)(lds + 16384 + arow + ko0);
    bf16x8 al01 = *(const bf16x8*)(lds + 16384 + arow + ko1);
    bf16x8 al10 = *(const bf16x8*)(lds + 16384 + arow + 2048 + ko0);
    bf16x8 al11 = *(const bf16x8*)(lds + 16384 + arow + 2048 + ko1);
    __syncthreads();                 // A reads done; [0,32K) free; tile0 drained

    float best[8], second[8];
    int   bidx[8];
    #pragma unroll
    for (int s = 0; s < 8; ++s) { best[s] = 3.4e38f; second[s] = 3.4e38f; bidx[s] = 0; }

    const int brow = (cg * 64 + lan15) * 256;  // + fc*4096 (imm)

    for (int ct = 0; ct < NCT; ++ct) {
        // cur: ct even -> Bs1 [32K), odd -> Bs0 [0); prefetch into the other
        char* cur = lds + ((ct & 1) ^ 1) * 32768;
        if (ct < NCT - 1) {
            char* nbuf = lds + (ct & 1) * 32768;
            const char* g = gb + (size_t)(ct + 1) * 32768;
#ifdef HAVE_GLD
            #pragma unroll
            for (int p = 0; p < 4; ++p)
                GLD16(nbuf + p * 8192 + t * 16, g + p * 8192 + t * 16);
#else
            #pragma unroll
            for (int p = 0; p < 4; ++p)
                *(uint4*)(nbuf + p * 8192 + t * 16) =
                    *(const uint4*)(g + p * 8192 + t * 16);
#endif
        }

        f32x4 acc[2][4];
        #pragma unroll
        for (int fr = 0; fr < 2; ++fr)
            #pragma unroll
            for (int fc = 0; fc < 4; ++fc)
                acc[fr][fc] = (f32x4){0.f, 0.f, 0.f, 0.f};

        // per-acc term order FP-identical to R6-R16: hh,hh,lh,lh,hl,hl
        #pragma unroll
        for (int fc = 0; fc < 4; ++fc) {
            const char* bp = cur + brow + fc * 4096;
            bf16x8 b0 = *(const bf16x8*)(bp + ko0);
            bf16x8 b1 = *(const bf16x8*)(bp + ko1);
            acc[0][fc] = __builtin_amdgcn_mfma_f32_16x16x32_bf16(ah00, b0, acc[0][fc], 0, 0, 0);
            acc[1][fc] = __builtin_amdgcn_mfma_f32_16x16x32_bf16(ah10, b0, acc[1][fc], 0, 0, 0);
            acc[0][fc] = __builtin_amdgcn_mfma_f32_16x16x32_bf16(ah01, b1, acc[0][fc], 0, 0, 0);
            acc[1][fc] = __builtin_amdgcn_mfma_f32_16x16x32_bf16(ah11, b1, acc[1][fc], 0, 0, 0);
            acc[0][fc] = __builtin_amdgcn_mfma_f32_16x16x32_bf16(al00, b0, acc[0][fc], 0, 0, 0);
            acc[1][fc] = __builtin_amdgcn_mfma_f32_16x16x32_bf16(al10, b0, acc[1][fc], 0, 0, 0);
            acc[0][fc] = __builtin_amdgcn_mfma_f32_16x16x32_bf16(al01, b1, acc[0][fc], 0, 0, 0);
            acc[1][fc] = __builtin_amdgcn_mfma_f32_16x16x32_bf16(al11, b1, acc[1][fc], 0, 0, 0);
            {
                bf16x8 b2 = *(const bf16x8*)(bp + 128 + ko0);
                acc[0][fc] = __builtin_amdgcn_mfma_f32_16x16x32_bf16(ah00, b2, acc[0][fc], 0, 0, 0);
                acc[1][fc] = __builtin_amdgcn_mfma_f32_16x16x32_bf16(ah10, b2, acc[1][fc], 0, 0, 0);
            }
            {
                bf16x8 b3 = *(const bf16x8*)(bp + 128 + ko1);
                acc[0][fc] = __builtin_amdgcn_mfma_f32_16x16x32_bf16(ah01, b3, acc[0][fc], 0, 0, 0);
                acc[1][fc] = __builtin_amdgcn_mfma_f32_16x16x32_bf16(ah11, b3, acc[1][fc], 0, 0, 0);
            }
        }

        // epilogue: u = esq/2 - dot; branchless (best, second, idx)
        #pragma unroll
        for (int fc = 0; fc < 4; ++fc) {
            int col = ct * BN + cg * 64 + fc * 16 + lan15;
            float eh = esqh_s[col];
            #pragma unroll
            for (int fr = 0; fr < 2; ++fr) {
                #pragma unroll
                for (int r = 0; r < 4; ++r) {
                    float u = eh - acc[fr][fc][r];
                    int s = fr * 4 + r;
                    second[s] = fminf(second[s], fmaxf(u, best[s]));
                    bidx[s] = (u < best[s]) ? col : bidx[s];
                    best[s] = fminf(u, best[s]);
                }
            }
        }
        __syncthreads();             // cur reads done; prefetch drained
    }

    // intra-wave reduce over 16-lane groups (lex: ties -> smaller col)
    #pragma unroll
    for (int s = 0; s < 8; ++s) {
        float b = best[s], sc = second[s];
        int bi = bidx[s];
        #pragma unroll
        for (int off = 1; off <= 8; off <<= 1) {
            float ob = __shfl_xor(b, off);
            float os = __shfl_xor(sc, off);
            int   oi = __shfl_xor(bi, off);
            float mx = fmaxf(b, ob);
            sc = fminf(fminf(sc, os), mx);
            if (ob < b) { b = ob; bi = oi; }
            else if (ob == b) bi = min(bi, oi);
        }
        best[s] = b; second[s] = sc; bidx[s] = bi;
    }
    if (lan15 == 0) {
        #pragma unroll
        for (int s = 0; s < 8; ++s) {
            int row = rg * 32 + (s >> 2) * 16 + (l >> 4) * 4 + (s & 3);
            cb_best[cg * BM + row] = best[s];
            cb_sec [cg * BM + row] = second[s];
            cb_idx [cg * BM + row] = bidx[s];
        }
    }
    __syncthreads();
    // cross-wave combine + flag emit
    if (t < BM) {
        float b0 = cb_best[t], b1 = cb_best[BM + t];
        float s0 = cb_sec[t],  s1 = cb_sec[BM + t];
        int   i0 = cb_idx[t],  i1 = cb_idx[BM + t];
        float b; int bi;
        if (b1 < b0 || (b1 == b0 && i1 < i0)) { b = b1; bi = i1; }
        else                                  { b = b0; bi = i0; }
        float sec = fminf(fminf(s0, s1), fmaxf(b0, b1));
        int gid = row0 + t;
        idx_out[gid] = (float)bi;
        bool flg = (sec - b <= EPS_U);
        fbi[t] = bi | (flg ? 0x80000000 : 0);
        unsigned long long mask = __ballot(flg);
        if (l == 0) bitmap[blockIdx.x * 2 + w] = mask;   // full-word, no init
        int nf = __popcll(mask);
        int base = 0;
        if (l == 0 && nf) base = atomicAdd(cnt, nf);
        base = __shfl(base, 0);
        if (flg) {
            int pos = __popcll(mask & ((1ull << l) - 1ull));
            int slot = base + pos;
            if (slot < SLOT_CAP) wl[slot] = gid;
        }
    }
    __syncthreads();                 // fbi visible to all waves

    // ---- fused gather tail: z_q_st rows + per-block loss partial ----
    {
        const int tk = t >> 2, qd = t & 3;
        int pk = fbi[tk];
        int bi = pk & 0x3FF;
        bool fl = pk < 0;
        const float4* zr = (const float4*)z + (size_t)(row0 + tk) * 16 + qd * 4;
        const float4* er = (const float4*)E + (size_t)bi * 16 + qd * 4;
        float4* orow = (float4*)out0 + (size_t)(row0 + tk) * 16 + qd * 4;
        float ls = 0.f;
        #pragma unroll
        for (int j = 0; j < 4; ++j) {
            float4 zv = zr[j], ev = er[j];
            float dx = ev.x - zv.x, dy = ev.y - zv.y;
            float dz = ev.z - zv.z, dw = ev.w - zv.w;
            float4 o = {zv.x + dx, zv.y + dy, zv.z + dz, zv.w + dw};
            orow[j] = o;
            ls += dx * dx + dy * dy + dz * dz + dw * dw;
        }
        if (fl) ls = 0.f;            // flagged: exact contrib comes from repair
        #pragma unroll
        for (int off = 1; off <= 32; off <<= 1) ls += __shfl_xor(ls, off);
        if (l == 0) wred[w] = ls;
    }
    __syncthreads();
    if (t == 0) {
        float s = 0.f;
        #pragma unroll
        for (int i = 0; i < 8; ++i) s += wred[i];
        partials[blockIdx.x] = s;
    }
}

// ---- K2: exact recompute, QUARTER-SPLIT (R2-pedigree staging + FMA chain)
__global__ __launch_bounds__(256) void fallback_kernel(
    const float* __restrict__ z, const float* __restrict__ E,
    const float* __restrict__ esq_g, unsigned long long* __restrict__ cand,
    const int* __restrict__ wl, const int* __restrict__ cnt_p) {
    __shared__ __align__(16) float es[DIM][128];   // 32KB [k][code]
    __shared__ __align__(16) float zl[16][72];     // padded
    __shared__ float zqs[16];

    const int t = threadIdx.x;
    const int tg = t >> 4;           // token slot 0..15
    const int cs = t & 15;           // code slice (8 codes per tile)
    const int cnt = min(*cnt_p, SLOT_CAP);
    const int nwork = ((cnt + 15) >> 4) << 2;      // chunks * 4 quarters

    for (int cb = blockIdx.x; cb < nwork; cb += 2048) {
        const int chunk = cb >> 2, qtr = cb & 3;
        const int base = chunk * 16;
        const int nval = min(16, cnt - base);
        const int tok = wl[base + (tg < nval ? tg : 0)];
        {
            float4 v = ((const float4*)z)[(size_t)tok * 16 + cs];
            *(float4*)&zl[tg][cs * 4] = v;
        }
        __syncthreads();
        if (t < 16) {                // zq per slot, sequential k (as R1)
            float s = 0.f;
            for (int k = 0; k < DIM; ++k) { float v = zl[t][k]; s += v * v; }
            zqs[t] = s;
        }
        __syncthreads();
        const float zq = zqs[tg];

        float best = 3.4e38f;
        int bi = 0;
        for (int ti = 0; ti < 2; ++ti) {         // 2 tiles of this quarter
            const int tile = qtr * 2 + ti;
            const float4* eg = (const float4*)(E + (size_t)tile * 128 * DIM);
            #pragma unroll
            for (int p = 0; p < 8; ++p) {        // R2 staging pattern verbatim
                int li = p * 256 + t;
                int c = li & 127, k4 = li >> 7;
                float4 v = eg[c * 16 + k4];
                es[k4 * 4 + 0][c] = v.x;
                es[k4 * 4 + 1][c] = v.y;
                es[k4 * 4 + 2][c] = v.z;
                es[k4 * 4 + 3][c] = v.w;
            }
            __syncthreads();

            float acc[8];
            #pragma unroll
            for (int n = 0; n < 8; ++n) acc[n] = 0.f;
            #pragma unroll 8
            for (int k = 0; k < DIM; ++k) {      // sequential fp32 FMA over K
                float a = zl[tg][k];
                float4 b0 = *(const float4*)&es[k][cs * 8 + 0];
                float4 b1 = *(const float4*)&es[k][cs * 8 + 4];
                float b[8] = {b0.x, b0.y, b0.z, b0.w, b1.x, b1.y, b1.z, b1.w};
                #pragma unroll
                for (int n = 0; n < 8; ++n) acc[n] += a * b[n];
            }
            #pragma unroll
            for (int n = 0; n < 8; ++n) {        // ascending code index, strict <
                int c = tile * 128 + cs * 8 + n;
                float d = (zq - 2.0f * acc[n]) + esq_g[c];
                if (d < best) { best = d; bi = c; }
            }
            __syncthreads();
        }
        #pragma unroll
        for (int off = 1; off <= 8; off <<= 1) {
            float ob = __shfl_xor(best, off);
            int   oi = __shfl_xor(bi, off);
            if (ob < best || (ob == best && oi < bi)) { best = ob; bi = oi; }
        }
        if (cs == 0 && tg < nval)
            cand[(size_t)(base + tg) * 4 + qtr] = packdi(best, bi);
        __syncthreads();
    }
}

// ---- K3: repair flagged tokens (u64-min of 4 quarter candidates)
__global__ __launch_bounds__(256) void repair_kernel(
    const float* __restrict__ z, const float* __restrict__ E,
    float* __restrict__ idx_out, float* __restrict__ out0,
    float* __restrict__ contrib, const unsigned long long* __restrict__ cand,
    const int* __restrict__ wl, const int* __restrict__ cnt_p) {
    const int t = threadIdx.x;
    const int tg = t >> 4;           // token slot 0..15
    const int cs = t & 15;           // float4 chunk of dim
    const int cnt = min(*cnt_p, SLOT_CAP);

    for (int s0 = blockIdx.x * 16; s0 < cnt; s0 += 512 * 16) {
        int s = s0 + tg;
        if (s < cnt) {
            int tok = wl[s];
            unsigned long long m = cand[(size_t)s * 4 + 0];
            m = min(m, cand[(size_t)s * 4 + 1]);
            m = min(m, cand[(size_t)s * 4 + 2]);
            m = min(m, cand[(size_t)s * 4 + 3]);
            int bi = (int)(unsigned)(m & 0xFFFFFFFFull);
            float4 zv = ((const float4*)z)[(size_t)tok * 16 + cs];
            float4 ev = ((const float4*)E)[(size_t)bi * 16 + cs];
            float dx = ev.x - zv.x, dy = ev.y - zv.y;
            float dz = ev.z - zv.z, dw = ev.w - zv.w;
            float4 o = {zv.x + dx, zv.y + dy, zv.z + dz, zv.w + dw};
            ((float4*)out0)[(size_t)tok * 16 + cs] = o;
            float c4 = dx * dx + dy * dy + dz * dz + dw * dw;
            #pragma unroll
            for (int off = 1; off <= 8; off <<= 1) c4 += __shfl_xor(c4, off);
            if (cs == 0) {
                idx_out[tok] = (float)bi;
                contrib[tok] = c4;
            }
        }
    }
}

// -------- K4: final loss = (sum partials + sum flagged contribs) scaled
__global__ __launch_bounds__(256) void loss_kernel(
    const float* __restrict__ partials, const unsigned long long* __restrict__ bitmap,
    const float* __restrict__ contrib, float* __restrict__ loss_out) {
    __shared__ float red[256];
    const int t = threadIdx.x;
    float p = 0.f;
    #pragma unroll
    for (int i = 0; i < 4; ++i) p += partials[t * 4 + i];
    for (int wi = t * 8; wi < t * 8 + 8; ++wi) {   // fixed token order per thread
        unsigned long long m = bitmap[wi];
        while (m) {
            int b = __builtin_ctzll(m);
            p += contrib[wi * 64 + b];
            m &= m - 1;
        }
    }
    red[t] = p;
    __syncthreads();
    for (int s = 128; s >= 1; s >>= 1) {
        if (t < s) red[t] += red[t + s];
        __syncthreads();
    }
    if (t == 0) {
        float m = red[0] / (float)(NTOK * DIM);
        loss_out[0] = m + 0.25f * m;
    }
}

extern "C" void kernel_launch(void* const* d_in, const int* in_sizes, int n_in,
                              void* d_out, int out_size, void* d_ws, size_t ws_size,
                              hipStream_t stream) {
    const float* z = (const float*)d_in[0];       // [131072, 64] f32
    const float* E = (const float*)d_in[1];       // [1024, 64] f32
    float* out = (float*)d_out;

    char* wsb = (char*)d_ws;
    float*              esq      = (float*)(wsb);               // 4 KB
    float*              esqh     = (float*)(wsb + 4096);        // 4 KB
    float*              partials = (float*)(wsb + 8192);        // 8 KB (1024 used)
    int*                cnt      = (int*)(wsb + 16384);         // 4 KB region
    int*                wl       = (int*)(wsb + 20480);         // 64 KB
    unsigned long long* bitmap   = (unsigned long long*)(wsb + 86016);  // 16 KB
    unsigned short*     Bswz     = (unsigned short*)(wsb + 102400);     // 256 KB
    float*              contrib  = (float*)(wsb + 364544);      // 512 KB
    unsigned long long* cand     = (unsigned long long*)(wsb + 888832); // 512 KB

    prep_kernel<<<256, 256, 0, stream>>>(E, Bswz, esqh, esq, cnt);
    mfma_argmin_kernel<<<NTOK / BM, 512, 0, stream>>>(z, E, Bswz, esqh,
                                                      out + IDX_OFF, out,
                                                      partials, cnt, wl, bitmap);
    fallback_kernel<<<2048, 256, 0, stream>>>(z, E, esq, cand, wl, cnt);
    repair_kernel<<<512, 256, 0, stream>>>(z, E, out + IDX_OFF, out, contrib,
                                           cand, wl, cnt);
    loss_kernel<<<1, 256, 0, stream>>>(partials, bitmap, contrib, out + LOSS_OFF);
}